// Round 6
// baseline (6395.036 us; speedup 1.0000x reference)
//
#include <hip/hip_runtime.h>

#define NB 2048     // batch
#define NT 10000    // time points
#define TPW 16      // trajectories per wave
#define NBLK (NB / TPW)   // 128 blocks, 1 wave each

// Builtin-exact f16 types: clang's AMDGPU builtins use 'h' == __fp16
// (cvt_pkrtz returns __fp16x2; mfma_*_f16 takes __fp16x8 — per R5 compile log).
typedef __fp16 half2_t __attribute__((ext_vector_type(2)));
typedef __fp16 half4_t __attribute__((ext_vector_type(4)));
typedef __fp16 half8_t __attribute__((ext_vector_type(8)));
typedef float  float4_t __attribute__((ext_vector_type(4)));

// DPP cross-lane (rows of 16): ~VALU-latency, no LDS pipe.
template <int CTRL>
__device__ __forceinline__ float dpp_f(float x) {
    return __int_as_float(__builtin_amdgcn_mov_dpp(__float_as_int(x), CTRL, 0xF, 0xF, true));
}
#define DPP_XOR1 0xB1   // quad_perm [1,0,3,2]
#define DPP_XOR2 0x4E   // quad_perm [2,3,0,1]
#define DPP_HMIR 0x141  // row_half_mirror
#define DPP_MIR  0x140  // row_mirror

__device__ __forceinline__ float fast_tanh_from_scaled(float pre_scaled) {
    // pre_scaled = 2*log2(e) * x  ->  tanh(x) = 1 - 2/(1 + e^{2x})
    float e = __builtin_amdgcn_exp2f(pre_scaled);
    return fmaf(-2.0f, __builtin_amdgcn_rcpf(1.0f + e), 1.0f);
}

// One wave integrates 16 trajectories, layer-2 via MFMA 16x16x32 f16.
// A-frag (M=16 traj, K=64 hid): lane holds rows m=lane&15, k = h*32 + (lane>>4)*8 + j
//   (j=0..7, frag h=0,1). Layer-1 computes h1 directly in this layout -> no relayout.
// B-frag: W2 preloaded with the SAME k-mapping (k-permutation consistency makes the
//   exact HW k-order irrelevant); col = tile*16 + (lane&15), 4 N-tiles.
// C/D layout (guide-verified, dtype-independent): col=lane&15, row=(lane>>4)*4+reg.
__global__ __launch_bounds__(64, 1) void hybrid_euler_kernel(
    const float* __restrict__ z0in,
    const float* __restrict__ t,
    const float* __restrict__ prm,
    const float* __restrict__ W1,
    const float* __restrict__ b1,
    const float* __restrict__ W2,
    const float* __restrict__ b2,
    const float* __restrict__ W3,
    const float* __restrict__ b3,
    float* __restrict__ out)
{
    const int lane  = threadIdx.x;
    const int tbase = blockIdx.x * TPW;
    const int m     = lane & 15;    // A-row (traj within wave) / C-col (hid within tile)
    const int kg    = lane >> 4;    // k-group

    const float S = 2.8853900817779268f; // 2 * log2(e)

    // ---- layer-1 constants: element jj -> k = (jj>=8 ? 32 : 0) + kg*8 + (jj&7) ----
    float w1a[16], w1b[16], b1c[16];
    #pragma unroll
    for (int jj = 0; jj < 16; ++jj) {
        const int k = ((jj >> 3) << 5) + kg * 8 + (jj & 7);
        w1a[jj] = W1[k]      * S;
        w1b[jj] = W1[64 + k] * S;
        b1c[jj] = b1[k]      * S;
    }

    // ---- W2 B-fragments (pre-scaled by S), 4 tiles x 2 k-frags x half8 ----
    half8_t w2f[4][2];
    #pragma unroll
    for (int tile = 0; tile < 4; ++tile) {
        const int col = tile * 16 + m;
        #pragma unroll
        for (int h = 0; h < 2; ++h) {
            half8_t f;
            #pragma unroll
            for (int e = 0; e < 8; ++e) {
                const int k = h * 32 + kg * 8 + e;
                f[e] = (__fp16)(W2[k * 64 + col] * S);
            }
            w2f[tile][h] = f;
        }
    }

    // ---- layer-2 bias (scaled, rides as MFMA C-in) and layer-3 weights ----
    float b2c[4], w3c[4];
    #pragma unroll
    for (int tile = 0; tile < 4; ++tile) {
        b2c[tile] = b2[tile * 16 + m] * S;
        w3c[tile] = W3[tile * 16 + m];
    }
    const float b3_16 = b3[0] * 0.0625f;   // b3/16: butterfly over 16 lanes re-adds it
    const float kappa = prm[0];
    const float mass  = prm[2];
    const float kmoM  = -kappa / mass;

    // z for this lane's trajectory (replicated across the 4 k-groups; stays in sync)
    float z0 = z0in[(tbase + m) * 2 + 0];
    float z1 = z0in[(tbase + m) * 2 + 1];

    if (lane < 16) {
        *(float2*)(out + (size_t)(tbase + lane) * 2) = make_float2(z0, z1);
    }

    // bpermute source: lane ((m>>2)*16 + m) holds accr[m&3] = nn[traj m]
    const int bpaddr = ((((m >> 2) << 4) + m) << 2);
    const bool sb0 = (lane & 1) != 0;
    const bool sb1 = (lane & 2) != 0;

    float tprev = t[0];
    float tcur  = t[1];
    float* optr = out + (size_t)NB * 2 + (size_t)tbase * 2;

    for (int s = 1; s < NT; ++s) {
        const float tnext = (s + 1 < NT) ? t[s + 1] : tcur;
        const float dt = tcur - tprev;

        // ---- layer 1: 16 activations per lane, already in A-frag layout ----
        float hv[16];
        #pragma unroll
        for (int jj = 0; jj < 16; ++jj) {
            const float pre = fmaf(z0, w1a[jj], fmaf(z1, w1b[jj], b1c[jj]));
            hv[jj] = fast_tanh_from_scaled(pre);
        }
        // pack to f16 pairs, concat via shufflevector (types match builtins exactly)
        const half2_t p0 = __builtin_amdgcn_cvt_pkrtz(hv[0],  hv[1]);
        const half2_t p1 = __builtin_amdgcn_cvt_pkrtz(hv[2],  hv[3]);
        const half2_t p2 = __builtin_amdgcn_cvt_pkrtz(hv[4],  hv[5]);
        const half2_t p3 = __builtin_amdgcn_cvt_pkrtz(hv[6],  hv[7]);
        const half2_t p4 = __builtin_amdgcn_cvt_pkrtz(hv[8],  hv[9]);
        const half2_t p5 = __builtin_amdgcn_cvt_pkrtz(hv[10], hv[11]);
        const half2_t p6 = __builtin_amdgcn_cvt_pkrtz(hv[12], hv[13]);
        const half2_t p7 = __builtin_amdgcn_cvt_pkrtz(hv[14], hv[15]);
        const half4_t q0 = __builtin_shufflevector(p0, p1, 0, 1, 2, 3);
        const half4_t q1 = __builtin_shufflevector(p2, p3, 0, 1, 2, 3);
        const half4_t q2 = __builtin_shufflevector(p4, p5, 0, 1, 2, 3);
        const half4_t q3 = __builtin_shufflevector(p6, p7, 0, 1, 2, 3);
        const half8_t a0 = __builtin_shufflevector(q0, q1, 0, 1, 2, 3, 4, 5, 6, 7);
        const half8_t a1 = __builtin_shufflevector(q2, q3, 0, 1, 2, 3, 4, 5, 6, 7);

        // ---- layer 2: 8 MFMA (4 N-tiles x 2 K-frags), bias as C-in ----
        float4_t acc[4];
        #pragma unroll
        for (int tile = 0; tile < 4; ++tile) {
            float4_t c = {b2c[tile], b2c[tile], b2c[tile], b2c[tile]};
            c = __builtin_amdgcn_mfma_f32_16x16x32_f16(a0, w2f[tile][0], c, 0, 0, 0);
            c = __builtin_amdgcn_mfma_f32_16x16x32_f16(a1, w2f[tile][1], c, 0, 0, 0);
            acc[tile] = c;
        }

        // ---- layer 3: tanh + per-lane fma, then row-of-16 butterfly allreduce ----
        // lane holds h2 for (traj=(lane>>4)*4+r, hid=tile*16+m)
        float accr0 = b3_16, accr1 = b3_16, accr2 = b3_16, accr3 = b3_16;
        #pragma unroll
        for (int tile = 0; tile < 4; ++tile) {
            accr0 = fmaf(fast_tanh_from_scaled(acc[tile][0]), w3c[tile], accr0);
            accr1 = fmaf(fast_tanh_from_scaled(acc[tile][1]), w3c[tile], accr1);
            accr2 = fmaf(fast_tanh_from_scaled(acc[tile][2]), w3c[tile], accr2);
            accr3 = fmaf(fast_tanh_from_scaled(acc[tile][3]), w3c[tile], accr3);
        }
        accr0 += dpp_f<DPP_XOR1>(accr0); accr0 += dpp_f<DPP_XOR2>(accr0);
        accr0 += dpp_f<DPP_HMIR>(accr0); accr0 += dpp_f<DPP_MIR>(accr0);
        accr1 += dpp_f<DPP_XOR1>(accr1); accr1 += dpp_f<DPP_XOR2>(accr1);
        accr1 += dpp_f<DPP_HMIR>(accr1); accr1 += dpp_f<DPP_MIR>(accr1);
        accr2 += dpp_f<DPP_XOR1>(accr2); accr2 += dpp_f<DPP_XOR2>(accr2);
        accr2 += dpp_f<DPP_HMIR>(accr2); accr2 += dpp_f<DPP_MIR>(accr2);
        accr3 += dpp_f<DPP_XOR1>(accr3); accr3 += dpp_f<DPP_XOR2>(accr3);
        accr3 += dpp_f<DPP_HMIR>(accr3); accr3 += dpp_f<DPP_MIR>(accr3);
        // accr[r] now = nn[(lane>>4)*4 + r], identical across each row of 16

        // route nn[traj=m] to this lane: select accr[m&3], pull from row m>>2
        const float s01  = sb0 ? accr1 : accr0;
        const float s23  = sb0 ? accr3 : accr2;
        const float vsel = sb1 ? s23 : s01;
        const float nn = __int_as_float(
            __builtin_amdgcn_ds_bpermute(bpaddr, __float_as_int(vsel)));

        // ---- Euler update (z0n uses OLD z1; z1n uses OLD z0) ----
        const float z1n = fmaf(dt, fmaf(kmoM, z0, nn), z1);
        const float z0n = fmaf(dt, z1, z0);
        z0 = z0n; z1 = z1n;

        if (lane < 16) {
            *(float2*)(optr + (size_t)lane * 2) = make_float2(z0, z1);
        }
        optr += (size_t)NB * 2;

        tprev = tcur;
        tcur  = tnext;
    }
}

extern "C" void kernel_launch(void* const* d_in, const int* in_sizes, int n_in,
                              void* d_out, int out_size, void* d_ws, size_t ws_size,
                              hipStream_t stream) {
    const float* z0 = (const float*)d_in[0];
    const float* t  = (const float*)d_in[1];
    const float* pp = (const float*)d_in[2];
    const float* W1 = (const float*)d_in[3];
    const float* b1 = (const float*)d_in[4];
    const float* W2 = (const float*)d_in[5];
    const float* b2 = (const float*)d_in[6];
    const float* W3 = (const float*)d_in[7];
    const float* b3 = (const float*)d_in[8];
    float* out = (float*)d_out;

    hybrid_euler_kernel<<<dim3(NBLK), dim3(64), 0, stream>>>(
        z0, t, pp, W1, b1, W2, b2, W3, b3, out);
}

// Round 7
// 5048.602 us; speedup vs baseline: 1.2667x; 1.2667x over previous
//
#include <hip/hip_runtime.h>

#define NB 2048     // batch
#define NT 10000    // time points

// Builtin-exact f16 types (clang AMDGPU builtins use __fp16)
typedef __fp16 half2_t __attribute__((ext_vector_type(2)));

__device__ __forceinline__ half2_t bch(int v) {
    return __builtin_bit_cast(half2_t, v);
}

// DPP cross-lane: ~VALU-latency, no LDS pipe. ctrl immediate -> template param.
template <int CTRL>
__device__ __forceinline__ float dpp_f(float x) {
    return __int_as_float(__builtin_amdgcn_mov_dpp(__float_as_int(x), CTRL, 0xF, 0xF, true));
}
#define DPP_XOR1 0xB1   // quad_perm [1,0,3,2]
#define DPP_XOR2 0x4E   // quad_perm [2,3,0,1]
#define DPP_HMIR 0x141  // row_half_mirror
#define DPP_MIR  0x140  // row_mirror
#define DPP_BC15 0x142  // row_bcast15
#define DPP_BC31 0x143  // row_bcast31

__device__ __forceinline__ float fast_tanh_from_scaled(float pre_scaled) {
    // pre_scaled = 2*log2(e) * x  ->  tanh(x) = 1 - 2/(1 + e^{2x})
    float e = __builtin_amdgcn_exp2f(pre_scaled);
    return fmaf(-2.0f, __builtin_amdgcn_rcpf(1.0f + e), 1.0f);
}

// K-split: block = 2 waves = 1 trajectory (4096 waves total, 4/SIMD).
// Both waves duplicate layer 1 (h1[unit=lane]) and the Euler update (z stays
// register-resident and bit-identical across all 128 threads).
// Layer 2: wave w owns units u = w*32+(lane&31); lane kh=lane>>5 sums k-half
// [kh*32,kh*32+32) via 16 dot2; halves combined with ds_bpermute(lane^32).
// Layer 3: per-wave DPP cascade -> lane63 partial -> LDS slot (parity dbuf)
// -> 1 barrier/step -> uniform b64 broadcast read -> nn in every thread.
__global__ __launch_bounds__(128, 4) void hybrid_euler_kernel(
    const float* __restrict__ z0in,
    const float* __restrict__ t,
    const float* __restrict__ prm,
    const float* __restrict__ W1,
    const float* __restrict__ b1,
    const float* __restrict__ W2,
    const float* __restrict__ b2,
    const float* __restrict__ W3,
    const float* __restrict__ b3,
    float* __restrict__ out)
{
    const int tid  = threadIdx.x;
    const int lane = tid & 63;
    const int w    = tid >> 6;          // wave id 0/1
    const int b    = blockIdx.x;        // trajectory

    const float S = 2.8853900817779268f; // 2 * log2(e)

    // ---- layer 1 constants (unit = lane), duplicated in both waves ----
    const float w1a = W1[lane]      * S;
    const float w1b = W1[64 + lane] * S;
    const float b1v = b1[lane]      * S;

    // ---- layer 2 assignment ----
    const int u  = w * 32 + (lane & 31);   // output unit
    const int kh = lane >> 5;              // k-half: [kh*32, kh*32+32)

    // W2 pairs for this lane: 16 packed f16 regs, pre-scaled by S
    int w2pk[16];
    #pragma unroll
    for (int j2 = 0; j2 < 16; ++j2) {
        const int k0 = kh * 32 + 2 * j2;
        half2_t p;
        p.x = (__fp16)(W2[k0 * 64 + u]       * S);
        p.y = (__fp16)(W2[(k0 + 1) * 64 + u] * S);
        w2pk[j2] = __builtin_bit_cast(int, p);
    }
    #pragma unroll
    for (int j2 = 0; j2 < 16; ++j2) asm volatile("" : "+v"(w2pk[j2]));

    // bias b2 added once per unit (kh==0 lane); pre2 = S*(b2[u] + sum)
    const float b2c = (kh == 0) ? b2[u] * S : 0.0f;
    // layer-3: each unit's h2 appears in 2 lanes -> fold 0.5 into W3
    const float w3c = W3[u] * 0.5f;
    // b3: 64 lanes x (b3/128) sum to b3/2 per wave; two waves -> b3
    const float b3_128 = b3[0] * 0.0078125f;

    const float kappa = prm[0];
    const float mass  = prm[2];
    const float kmoM  = -kappa / mass;

    // per-wave h1 pair regions (widx dummy trick: odd lanes -> words 32..63)
    __shared__ alignas(16) int hbuf[2][64];
    // nn partial slots: [parity][wave]
    __shared__ float nslot[2][2];

    float z0 = z0in[b * 2 + 0];
    float z1 = z0in[b * 2 + 1];

    if (tid == 0) {
        *(float2*)(out + (size_t)b * 2) = make_float2(z0, z1);
    }

    const int widx = (lane >> 1) + ((lane & 1) << 5);  // even->0..31, odd->32..63
    const int bpaddr = (lane ^ 32) << 2;               // half-swap source

    float tprev = t[0];
    float tcur  = t[1];
    float* optr = out + (size_t)NB * 2 + (size_t)b * 2;

    for (int s = 1; s < NT; ++s) {
        const float tnext = (s + 1 < NT) ? t[s + 1] : tcur;
        const float dt = tcur - tprev;
        const int par = s & 1;

        // ---- layer 1 (duplicated): h1[unit=lane] ----
        const float pre1 = fmaf(z0, w1a, fmaf(z1, w1b, b1v));
        const float h1 = fast_tanh_from_scaled(pre1);

        // ---- pack pairs via DPP quad swap; even lane 2j: (h1[2j], h1[2j+1]) ----
        const float h1n = dpp_f<DPP_XOR1>(h1);
        const int hpi = __builtin_bit_cast(int,
            __builtin_amdgcn_cvt_pkrtz(h1, h1n));

        // ---- within-wave broadcast through wave-private LDS region ----
        hbuf[w][widx] = hpi;
        asm volatile("" ::: "memory");   // pin write-before-read (wave lockstep)
        int hp[16];
        #pragma unroll
        for (int i = 0; i < 4; ++i) {
            int4 v;
            __builtin_memcpy(&v, &hbuf[w][kh * 16 + 4 * i], 16); // ds_read_b128
            hp[4 * i + 0] = v.x;
            hp[4 * i + 1] = v.y;
            hp[4 * i + 2] = v.z;
            hp[4 * i + 3] = v.w;
        }

        // ---- layer 2: 16 dot2 (4 chains), then K-half combine via bpermute ----
        float ac0 = b2c, ac1 = 0.0f, ac2 = 0.0f, ac3 = 0.0f;
        #pragma unroll
        for (int jo = 0; jo < 4; ++jo) {
            ac0 = __builtin_amdgcn_fdot2(bch(hp[4*jo+0]), bch(w2pk[4*jo+0]), ac0, false);
            ac1 = __builtin_amdgcn_fdot2(bch(hp[4*jo+1]), bch(w2pk[4*jo+1]), ac1, false);
            ac2 = __builtin_amdgcn_fdot2(bch(hp[4*jo+2]), bch(w2pk[4*jo+2]), ac2, false);
            ac3 = __builtin_amdgcn_fdot2(bch(hp[4*jo+3]), bch(w2pk[4*jo+3]), ac3, false);
        }
        const float preh = (ac0 + ac1) + (ac2 + ac3);
        const float porto = __int_as_float(
            __builtin_amdgcn_ds_bpermute(bpaddr, __float_as_int(preh)));
        const float pre2 = preh + porto;
        const float h2 = fast_tanh_from_scaled(pre2);

        // ---- layer 3: per-wave DPP reduce cascade; lane63 = wave partial ----
        float pr = fmaf(h2, w3c, b3_128);
        pr += dpp_f<DPP_XOR1>(pr);
        pr += dpp_f<DPP_XOR2>(pr);
        pr += dpp_f<DPP_HMIR>(pr);
        pr += dpp_f<DPP_MIR>(pr);   // row-of-16 sums
        pr += dpp_f<DPP_BC15>(pr);
        pr += dpp_f<DPP_BC31>(pr);  // lane63 = full-wave partial (incl b3/2)

        if (lane == 63) nslot[par][w] = pr;
        // LDS-only drain + exec barrier (no vmcnt: only LDS crosses the barrier)
        asm volatile("s_waitcnt lgkmcnt(0)\n\ts_barrier" ::: "memory");
        float2 ns;
        __builtin_memcpy(&ns, &nslot[par][0], 8);   // uniform b64 broadcast read
        const float nn = ns.x + ns.y;

        // ---- Euler update (identical in all 128 threads; stays in sync) ----
        const float z1n = fmaf(dt, fmaf(kmoM, z0, nn), z1);
        const float z0n = fmaf(dt, z1, z0);
        z0 = z0n; z1 = z1n;

        if (tid == 0) {
            *(float2*)optr = make_float2(z0, z1);
        }
        optr += (size_t)NB * 2;

        tprev = tcur;
        tcur  = tnext;
    }
}

extern "C" void kernel_launch(void* const* d_in, const int* in_sizes, int n_in,
                              void* d_out, int out_size, void* d_ws, size_t ws_size,
                              hipStream_t stream) {
    const float* z0 = (const float*)d_in[0];
    const float* t  = (const float*)d_in[1];
    const float* pp = (const float*)d_in[2];
    const float* W1 = (const float*)d_in[3];
    const float* b1 = (const float*)d_in[4];
    const float* W2 = (const float*)d_in[5];
    const float* b2 = (const float*)d_in[6];
    const float* W3 = (const float*)d_in[7];
    const float* b3 = (const float*)d_in[8];
    float* out = (float*)d_out;

    hybrid_euler_kernel<<<dim3(NB), dim3(128), 0, stream>>>(
        z0, t, pp, W1, b1, W2, b2, W3, b3, out);
}

// Round 8
// 2967.144 us; speedup vs baseline: 2.1553x; 1.7015x over previous
//
#include <hip/hip_runtime.h>

#define NB 2048     // batch
#define NT 10000    // time points

// Builtin-exact f16 types (clang AMDGPU builtins use __fp16 — R5 compile log)
typedef __fp16 half2_t __attribute__((ext_vector_type(2)));
typedef __fp16 half8_t __attribute__((ext_vector_type(8)));
typedef float  float4_t __attribute__((ext_vector_type(4)));

// DPP cross-lane (rows of 16): ~VALU-latency, no LDS pipe.
template <int CTRL>
__device__ __forceinline__ float dpp_f(float x) {
    return __int_as_float(__builtin_amdgcn_mov_dpp(__float_as_int(x), CTRL, 0xF, 0xF, true));
}
#define DPP_XOR1 0xB1   // quad_perm [1,0,3,2]
#define DPP_XOR2 0x4E   // quad_perm [2,3,0,1]
#define DPP_HMIR 0x141  // row_half_mirror
#define DPP_MIR  0x140  // row_mirror

__device__ __forceinline__ float fast_tanh_from_scaled(float pre_scaled) {
    // pre_scaled = 2*log2(e) * x  ->  tanh(x) = 1 - 2/(1 + e^{2x})
    float e = __builtin_amdgcn_exp2f(pre_scaled);
    return fmaf(-2.0f, __builtin_amdgcn_rcpf(1.0f + e), 1.0f);
}

// One wave = one trajectory (2048 waves, 2/SIMD). Layer 2 via MFMA 16x16x32 f16
// used as a broadcast-reduce engine:
//   A (16x32 per frag): ALL 16 rows = h1 chunk. Lane (m=lane&15, kg=lane>>4)
//     loads its 8 k-values (k = h*32 + kg*8 + j) with ONE ds_read_b128 per frag
//     from the packed-pair h1 buffer — address depends only on kg -> 16-lane
//     broadcast reads, conflict-free, rows identical by construction.
//   B: W2 with the SAME logical k-map (permutation cancels), col = tile*16+m.
//   C: col = lane&15 -> unit u = tile*16+m; all 4 row-regs identical (A rows
//     equal) -> take reg 0. Lane m holds pre2 for units {m,16+m,32+m,48+m}.
// Layer 3: 4 tanh + 4 fma per lane, then 4-stage row-of-16 DPP all-reduce
// -> nn lands in EVERY lane (kg-rows are replicas): no readlane, no barrier.
__global__ __launch_bounds__(64, 2) void hybrid_euler_kernel(
    const float* __restrict__ z0in,
    const float* __restrict__ t,
    const float* __restrict__ prm,
    const float* __restrict__ W1,
    const float* __restrict__ b1,
    const float* __restrict__ W2,
    const float* __restrict__ b2,
    const float* __restrict__ W3,
    const float* __restrict__ b3,
    float* __restrict__ out)
{
    const int lane = threadIdx.x;        // one wave per block
    const int b    = blockIdx.x;         // trajectory index
    const int m    = lane & 15;          // C-col / A-row id
    const int kg   = lane >> 4;          // k-group

    const float S = 2.8853900817779268f; // 2 * log2(e)

    // ---- layer-1 constants (unit = lane) ----
    const float w1a = W1[lane]      * S;
    const float w1b = W1[64 + lane] * S;
    const float b1v = b1[lane]      * S;

    // ---- W2 B-fragments (pre-scaled by S): 4 N-tiles x 2 K-frags ----
    half8_t w2f[4][2];
    #pragma unroll
    for (int tile = 0; tile < 4; ++tile) {
        const int col = tile * 16 + m;
        #pragma unroll
        for (int h = 0; h < 2; ++h) {
            half8_t f;
            #pragma unroll
            for (int e = 0; e < 8; ++e) {
                const int k = h * 32 + kg * 8 + e;
                f[e] = (__fp16)(W2[k * 64 + col] * S);
            }
            w2f[tile][h] = f;
        }
    }

    // ---- layer-2 bias (rides as MFMA C-in) and layer-3 weights ----
    float b2c[4], w3c[4];
    #pragma unroll
    for (int tile = 0; tile < 4; ++tile) {
        b2c[tile] = b2[tile * 16 + m] * S;
        w3c[tile] = W3[tile * 16 + m];
    }
    const float b3_16 = b3[0] * 0.0625f;  // b3/16: row-of-16 reduce re-sums to b3
    const float kappa = prm[0];
    const float mass  = prm[2];
    const float kmoM  = -kappa / mass;

    // packed h1 pairs; odd lanes write junk to words 32..63 (no divergent branch)
    __shared__ alignas(16) int hbuf[64];

    float z0 = z0in[b * 2 + 0];
    float z1 = z0in[b * 2 + 1];

    if (lane == 0) {
        *(float2*)(out + (size_t)b * 2) = make_float2(z0, z1);
    }

    const int widx = (lane >> 1) + ((lane & 1) << 5);  // even->0..31, odd->32..63

    float tprev = t[0];
    float tcur  = t[1];
    float* optr = out + (size_t)NB * 2 + (size_t)b * 2;

    for (int s = 1; s < NT; ++s) {
        const float tnext = (s + 1 < NT) ? t[s + 1] : tcur;
        const float dt = tcur - tprev;

        // ---- layer 1: h1[unit=lane], one tanh per lane ----
        const float pre1 = fmaf(z0, w1a, fmaf(z1, w1b, b1v));
        const float h1 = fast_tanh_from_scaled(pre1);

        // ---- pack pairs via DPP quad swap; even lane 2j holds (h1[2j],h1[2j+1]) ----
        const float h1n = dpp_f<DPP_XOR1>(h1);
        const int hpi = __builtin_bit_cast(int,
            __builtin_amdgcn_cvt_pkrtz(h1, h1n));

        // ---- broadcast through LDS: 1 ds_write + 2 broadcast ds_read_b128 ----
        hbuf[widx] = hpi;
        asm volatile("" ::: "memory");   // pin write-before-read (wave lockstep)
        half8_t a0, a1;
        __builtin_memcpy(&a0, &hbuf[kg * 4],      16);  // k = kg*8 + 0..7
        __builtin_memcpy(&a1, &hbuf[16 + kg * 4], 16);  // k = 32 + kg*8 + 0..7

        // ---- layer 2: 8 MFMA (4 N-tiles x 2 K-frags), bias as C-in ----
        float4_t acc[4];
        #pragma unroll
        for (int tile = 0; tile < 4; ++tile) {
            float4_t c = {b2c[tile], b2c[tile], b2c[tile], b2c[tile]};
            c = __builtin_amdgcn_mfma_f32_16x16x32_f16(a0, w2f[tile][0], c, 0, 0, 0);
            c = __builtin_amdgcn_mfma_f32_16x16x32_f16(a1, w2f[tile][1], c, 0, 0, 0);
            acc[tile] = c;
        }

        // ---- layer 3: 4 tanh + 4 fma, then 4-stage row-of-16 DPP all-reduce ----
        float p = b3_16;
        #pragma unroll
        for (int tile = 0; tile < 4; ++tile) {
            p = fmaf(fast_tanh_from_scaled(acc[tile][0]), w3c[tile], p);
        }
        p += dpp_f<DPP_XOR1>(p);
        p += dpp_f<DPP_XOR2>(p);
        p += dpp_f<DPP_HMIR>(p);
        p += dpp_f<DPP_MIR>(p);   // every lane: sum over its row of 16 = all 64 units
        const float nn = p;

        // ---- Euler update (z0n uses OLD z1; z1n uses OLD z0) ----
        const float z1n = fmaf(dt, fmaf(kmoM, z0, nn), z1);
        const float z0n = fmaf(dt, z1, z0);
        z0 = z0n; z1 = z1n;

        if (lane == 0) {
            *(float2*)optr = make_float2(z0, z1);
        }
        optr += (size_t)NB * 2;

        tprev = tcur;
        tcur  = tnext;
    }
}

extern "C" void kernel_launch(void* const* d_in, const int* in_sizes, int n_in,
                              void* d_out, int out_size, void* d_ws, size_t ws_size,
                              hipStream_t stream) {
    const float* z0 = (const float*)d_in[0];
    const float* t  = (const float*)d_in[1];
    const float* pp = (const float*)d_in[2];
    const float* W1 = (const float*)d_in[3];
    const float* b1 = (const float*)d_in[4];
    const float* W2 = (const float*)d_in[5];
    const float* b2 = (const float*)d_in[6];
    const float* W3 = (const float*)d_in[7];
    const float* b3 = (const float*)d_in[8];
    float* out = (float*)d_out;

    hybrid_euler_kernel<<<dim3(NB), dim3(64), 0, stream>>>(
        z0, t, pp, W1, b1, W2, b2, W3, b3, out);
}

// Round 11
// 2599.629 us; speedup vs baseline: 2.4600x; 1.1414x over previous
//
#include <hip/hip_runtime.h>

#define NB 2048     // batch
#define NT 10000    // time points

// Builtin-exact f16 types (clang AMDGPU builtins use __fp16 — R5 compile log)
typedef __fp16 half2_t __attribute__((ext_vector_type(2)));
typedef __fp16 half8_t __attribute__((ext_vector_type(8)));
typedef float  float4_t __attribute__((ext_vector_type(4)));

// DPP cross-lane (rows of 16): ~VALU-latency, no LDS pipe.
template <int CTRL>
__device__ __forceinline__ float dpp_f(float x) {
    return __int_as_float(__builtin_amdgcn_mov_dpp(__float_as_int(x), CTRL, 0xF, 0xF, true));
}
#define DPP_XOR1 0xB1   // quad_perm [1,0,3,2]
#define DPP_XOR2 0x4E   // quad_perm [2,3,0,1]
#define DPP_HMIR 0x141  // row_half_mirror
#define DPP_MIR  0x140  // row_mirror
#define DPP_BC15 0x142  // row_bcast15
#define DPP_BC31 0x143  // row_bcast31

__device__ __forceinline__ float readlane_f(float v, int l) {
    return __int_as_float(__builtin_amdgcn_readlane(__float_as_int(v), l));
}

__device__ __forceinline__ float fast_tanh_from_scaled(float pre_scaled) {
    // pre_scaled = 2*log2(e) * x  ->  tanh(x) = 1 - 2/(1 + e^{2x})
    float e = __builtin_amdgcn_exp2f(pre_scaled);
    return fmaf(-2.0f, __builtin_amdgcn_rcpf(1.0f + e), 1.0f);
}

// One wave = one trajectory (2048 waves, 2/SIMD). Layer 2 via MFMA 16x16x32 f16
// as a broadcast-reduce engine (R8-proven):
//   A: all 16 rows = h1 chunk (2 broadcast ds_read_b128 from packed-pair buffer).
//   B: W2, same logical k-map (permutation cancels), col = tile*16 + (lane&15).
//   C-in: loop-invariant bias quads cb[tile] (hoisted: no per-step v_movs).
//   C rows identical -> lane (m,kg) selects acc[kg][0] = biased pre2 of unit
//   u = kg*16+m = lane. ONE tanh per lane (was 4), then 6-stage DPP reduce
//   (R2-proven sequence) -> lane63 total -> readlane -> scalar nn.
__global__ __launch_bounds__(64, 2) void hybrid_euler_kernel(
    const float* __restrict__ z0in,
    const float* __restrict__ t,
    const float* __restrict__ prm,
    const float* __restrict__ W1,
    const float* __restrict__ b1,
    const float* __restrict__ W2,
    const float* __restrict__ b2,
    const float* __restrict__ W3,
    const float* __restrict__ b3,
    float* __restrict__ out)
{
    const int lane = threadIdx.x;        // one wave per block
    const int b    = blockIdx.x;         // trajectory index
    const int m    = lane & 15;          // C-col / A-row id
    const int kg   = lane >> 4;          // k-group (also this lane's N-tile)

    const float S = 2.8853900817779268f; // 2 * log2(e)

    // ---- layer-1 constants (unit = lane) ----
    const float w1a = W1[lane]      * S;
    const float w1b = W1[64 + lane] * S;
    const float b1v = b1[lane]      * S;

    // ---- W2 B-fragments (pre-scaled by S): 4 N-tiles x 2 K-frags ----
    half8_t w2f[4][2];
    #pragma unroll
    for (int tile = 0; tile < 4; ++tile) {
        const int col = tile * 16 + m;
        #pragma unroll
        for (int h = 0; h < 2; ++h) {
            half8_t f;
            #pragma unroll
            for (int e = 0; e < 8; ++e) {
                const int k = h * 32 + kg * 8 + e;
                f[e] = (__fp16)(W2[k * 64 + col] * S);
            }
            w2f[tile][h] = f;
        }
    }

    // ---- loop-invariant bias quads (MFMA C-in; hoisted out of the loop) ----
    float4_t cb[4];
    #pragma unroll
    for (int tile = 0; tile < 4; ++tile) {
        const float v = b2[tile * 16 + m] * S;
        float4_t q;
        q[0] = v; q[1] = v; q[2] = v; q[3] = v;
        cb[tile] = q;
    }

    // ---- layer-3 per-lane constants (unit = lane) ----
    const float w3v   = W3[lane];
    const float b3_64 = b3[0] * 0.015625f;  // b3/64: 64-lane reduce re-sums to b3
    const float kappa = prm[0];
    const float mass  = prm[2];
    const float kmoM  = -kappa / mass;

    // packed h1 pairs; odd lanes write junk to words 32..63 (no divergent branch)
    __shared__ alignas(16) int hbuf[64];

    float z0 = z0in[b * 2 + 0];
    float z1 = z0in[b * 2 + 1];

    if (lane == 0) {
        *(float2*)(out + (size_t)b * 2) = make_float2(z0, z1);
    }

    const int widx = (lane >> 1) + ((lane & 1) << 5);  // even->0..31, odd->32..63
    const bool kb0 = (lane & 16) != 0;
    const bool kb1 = (lane & 32) != 0;

    float tprev = t[0];
    float tcur  = t[1];
    float* optr = out + (size_t)NB * 2 + (size_t)b * 2;

    for (int s = 1; s < NT; ++s) {
        const float tnext = (s + 1 < NT) ? t[s + 1] : tcur;
        const float dt = tcur - tprev;

        // ---- layer 1: h1[unit=lane], one tanh per lane ----
        const float pre1 = fmaf(z0, w1a, fmaf(z1, w1b, b1v));
        const float h1 = fast_tanh_from_scaled(pre1);

        // ---- pack pairs via DPP quad swap; even lane 2j holds (h1[2j],h1[2j+1]) ----
        const float h1n = dpp_f<DPP_XOR1>(h1);
        const int hpi = __builtin_bit_cast(int,
            __builtin_amdgcn_cvt_pkrtz(h1, h1n));

        // ---- broadcast through LDS: 1 ds_write + 2 broadcast ds_read_b128 ----
        hbuf[widx] = hpi;
        asm volatile("" ::: "memory");   // pin write-before-read (wave lockstep)
        half8_t a0, a1;
        __builtin_memcpy(&a0, &hbuf[kg * 4],      16);  // k = kg*8 + 0..7
        __builtin_memcpy(&a1, &hbuf[16 + kg * 4], 16);  // k = 32 + kg*8 + 0..7

        // ---- layer 2: 8 MFMA (4 N-tiles x 2 K-frags), hoisted bias as C-in ----
        float4_t acc[4];
        #pragma unroll
        for (int tile = 0; tile < 4; ++tile) {
            acc[tile] = __builtin_amdgcn_mfma_f32_16x16x32_f16(
                a1, w2f[tile][1],
                __builtin_amdgcn_mfma_f32_16x16x32_f16(a0, w2f[tile][0], cb[tile], 0, 0, 0),
                0, 0, 0);
        }

        // ---- layer 3: this lane owns unit u = lane -> select acc[kg][0] ----
        const float a01 = kb0 ? acc[1][0] : acc[0][0];
        const float a23 = kb0 ? acc[3][0] : acc[2][0];
        const float pre2 = kb1 ? a23 : a01;          // biased, S-scaled
        const float h2 = fast_tanh_from_scaled(pre2);
        float p = fmaf(h2, w3v, b3_64);

        // 6-stage reduce (R2-proven): row sums then bcast cascade -> lane63 total
        p += dpp_f<DPP_XOR1>(p);
        p += dpp_f<DPP_XOR2>(p);
        p += dpp_f<DPP_HMIR>(p);
        p += dpp_f<DPP_MIR>(p);
        p += dpp_f<DPP_BC15>(p);
        p += dpp_f<DPP_BC31>(p);
        const float nn = readlane_f(p, 63);

        // ---- Euler update (z0n uses OLD z1; z1n uses OLD z0) ----
        const float z1n = fmaf(dt, fmaf(kmoM, z0, nn), z1);
        const float z0n = fmaf(dt, z1, z0);
        z0 = z0n; z1 = z1n;

        if (lane == 0) {
            *(float2*)optr = make_float2(z0, z1);
        }
        optr += (size_t)NB * 2;

        tprev = tcur;
        tcur  = tnext;
    }
}

extern "C" void kernel_launch(void* const* d_in, const int* in_sizes, int n_in,
                              void* d_out, int out_size, void* d_ws, size_t ws_size,
                              hipStream_t stream) {
    const float* z0 = (const float*)d_in[0];
    const float* t  = (const float*)d_in[1];
    const float* pp = (const float*)d_in[2];
    const float* W1 = (const float*)d_in[3];
    const float* b1 = (const float*)d_in[4];
    const float* W2 = (const float*)d_in[5];
    const float* b2 = (const float*)d_in[6];
    const float* W3 = (const float*)d_in[7];
    const float* b3 = (const float*)d_in[8];
    float* out = (float*)d_out;

    hybrid_euler_kernel<<<dim3(NB), dim3(64), 0, stream>>>(
        z0, t, pp, W1, b1, W2, b2, W3, b3, out);
}